// Round 1
// baseline (253.031 us; speedup 1.0000x reference)
//
#include <hip/hip_runtime.h>

// MeshConvPoint: B=8, C=64, V=25000, D=12, O=64
// out[b,o,v] = bias[o] + sum_c W0[o,c]*x[b,c,v] + (1/deg_v) * sum_{d<deg} y1[b,o,nbr[b,v,d]]
// with y1 = W1 @ x, materialized v-major (y1T[b][v][o]) so neighbor gathers are
// contiguous 256B rows.

#define NB 8
#define NC 64
#define NV 25000
#define ND 12
#define NO 64

// ---------------- K0: transpose W[o][c][k] -> Wt[k][c][o] (8192 elems) ----------------
__global__ __launch_bounds__(256) void wt_kernel(const float* __restrict__ W,
                                                 float* __restrict__ Wt) {
    int i = blockIdx.x * 256 + threadIdx.x;  // [k][c][o]
    int k = i >> 12;
    int c = (i >> 6) & 63;
    int o = i & 63;
    Wt[i] = W[o * (NC * 2) + c * 2 + k];
}

// ---------------- K1: y1T[b][v][o] = sum_c W1[o][c] * x[b][c][v] ----------------
// lane = v; x column in 64 VGPRs; W via uniform (scalar) loads; output in 16-o chunks.
__global__ __launch_bounds__(256) void y1_kernel(const float* __restrict__ x,
                                                 const float* __restrict__ Wt,
                                                 float* __restrict__ y1) {
    const int b = blockIdx.y;
    const int v = blockIdx.x * 256 + threadIdx.x;
    const int vc = v < NV ? v : NV - 1;
    const bool valid = (v < NV);

    const float* xb = x + (size_t)b * NC * NV;
    float xr[NC];
#pragma unroll
    for (int c = 0; c < NC; ++c) xr[c] = xb[(size_t)c * NV + vc];

    const float* Wt1 = Wt + NC * NO;  // k=1 plane, layout [c][o]
    float* yrow = y1 + ((size_t)b * NV + vc) * NO;

#pragma unroll 1
    for (int oc = 0; oc < NO; oc += 16) {
        float acc[16];
#pragma unroll
        for (int j = 0; j < 16; ++j) acc[j] = 0.0f;
#pragma unroll
        for (int c = 0; c < NC; ++c) {
            const float xc = xr[c];
#pragma unroll
            for (int j = 0; j < 16; ++j)
                acc[j] = __builtin_fmaf(Wt1[c * NO + oc + j], xc, acc[j]);
        }
        if (valid) {
#pragma unroll
            for (int j = 0; j < 16; j += 4) {
                float4 t = make_float4(acc[j], acc[j + 1], acc[j + 2], acc[j + 3]);
                *reinterpret_cast<float4*>(yrow + oc + j) = t;
            }
        }
    }
}

// ---------------- K2: out = bias + W0@x + invdeg * gather-sum(y1T) ----------------
__global__ __launch_bounds__(256) void out_kernel(const float* __restrict__ x,
                                                  const int* __restrict__ nbr,
                                                  const int* __restrict__ deg,
                                                  const float* __restrict__ Wt,
                                                  const float* __restrict__ bias,
                                                  const float* __restrict__ y1,
                                                  float* __restrict__ out) {
    const int b = blockIdx.y;
    const int v = blockIdx.x * 256 + threadIdx.x;
    const int vc = v < NV ? v : NV - 1;
    const bool valid = (v < NV);

    const float* xb = x + (size_t)b * NC * NV;
    float xr[NC];
#pragma unroll
    for (int c = 0; c < NC; ++c) xr[c] = xb[(size_t)c * NV + vc];

    const size_t bv = (size_t)b * NV + vc;
    int idxr[ND];
    {
        const int4* p = reinterpret_cast<const int4*>(nbr + bv * ND);
        int4 a0 = p[0], a1 = p[1], a2 = p[2];
        idxr[0] = a0.x; idxr[1] = a0.y; idxr[2]  = a0.z; idxr[3]  = a0.w;
        idxr[4] = a1.x; idxr[5] = a1.y; idxr[6]  = a1.z; idxr[7]  = a1.w;
        idxr[8] = a2.x; idxr[9] = a2.y; idxr[10] = a2.z; idxr[11] = a2.w;
    }
    const int degv = deg[bv];
    const float invdeg = 1.0f / (float)degv;
    const float* y1b = y1 + ((size_t)b * NV) * NO;

#pragma unroll 1
    for (int oc = 0; oc < NO; oc += 16) {
        float acc[16];
#pragma unroll
        for (int j = 0; j < 16; ++j) acc[j] = bias[oc + j];

        // self term: W0 @ x
#pragma unroll
        for (int c = 0; c < NC; ++c) {
            const float xc = xr[c];
#pragma unroll
            for (int j = 0; j < 16; ++j)
                acc[j] = __builtin_fmaf(Wt[c * NO + oc + j], xc, acc[j]);
        }

        // neighbor term: gather contiguous 64B pieces of y1T rows (exec-masked)
#pragma unroll
        for (int d = 0; d < ND; ++d) {
            if (d < degv) {
                const float* row = y1b + ((size_t)idxr[d] << 6) + oc;
                const float4 g0 = *reinterpret_cast<const float4*>(row);
                const float4 g1 = *reinterpret_cast<const float4*>(row + 4);
                const float4 g2 = *reinterpret_cast<const float4*>(row + 8);
                const float4 g3 = *reinterpret_cast<const float4*>(row + 12);
                acc[0]  = __builtin_fmaf(invdeg, g0.x, acc[0]);
                acc[1]  = __builtin_fmaf(invdeg, g0.y, acc[1]);
                acc[2]  = __builtin_fmaf(invdeg, g0.z, acc[2]);
                acc[3]  = __builtin_fmaf(invdeg, g0.w, acc[3]);
                acc[4]  = __builtin_fmaf(invdeg, g1.x, acc[4]);
                acc[5]  = __builtin_fmaf(invdeg, g1.y, acc[5]);
                acc[6]  = __builtin_fmaf(invdeg, g1.z, acc[6]);
                acc[7]  = __builtin_fmaf(invdeg, g1.w, acc[7]);
                acc[8]  = __builtin_fmaf(invdeg, g2.x, acc[8]);
                acc[9]  = __builtin_fmaf(invdeg, g2.y, acc[9]);
                acc[10] = __builtin_fmaf(invdeg, g2.z, acc[10]);
                acc[11] = __builtin_fmaf(invdeg, g2.w, acc[11]);
                acc[12] = __builtin_fmaf(invdeg, g3.x, acc[12]);
                acc[13] = __builtin_fmaf(invdeg, g3.y, acc[13]);
                acc[14] = __builtin_fmaf(invdeg, g3.z, acc[14]);
                acc[15] = __builtin_fmaf(invdeg, g3.w, acc[15]);
            }
        }

        if (valid) {
#pragma unroll
            for (int j = 0; j < 16; ++j)
                out[((size_t)b * NO + oc + j) * NV + v] = acc[j];  // coalesced along v
        }
    }
}

// ---------------- Fallback (workspace too small): correct but slow ----------------
__global__ __launch_bounds__(64) void fallback_kernel(const float* __restrict__ x,
                                                      const int* __restrict__ nbr,
                                                      const int* __restrict__ deg,
                                                      const float* __restrict__ W,
                                                      const float* __restrict__ bias,
                                                      float* __restrict__ out) {
    const int bvi = blockIdx.x;
    const int b = bvi / NV, v = bvi % NV;
    const int o = threadIdx.x;
    const int degv = deg[bvi];
    const float inv = 1.0f / (float)degv;
    float acc = bias[o];
    for (int c = 0; c < NC; ++c) {
        const float* xc = x + ((size_t)b * NC + c) * NV;
        float m = 0.0f;
        for (int d = 0; d < degv; ++d) m += xc[nbr[(size_t)bvi * ND + d]];
        acc += W[o * (NC * 2) + c * 2] * xc[v] + W[o * (NC * 2) + c * 2 + 1] * (m * inv);
    }
    out[((size_t)b * NO + o) * NV + v] = acc;
}

extern "C" void kernel_launch(void* const* d_in, const int* in_sizes, int n_in,
                              void* d_out, int out_size, void* d_ws, size_t ws_size,
                              hipStream_t stream) {
    const float* x    = (const float*)d_in[0];
    const int*   nbr  = (const int*)d_in[1];
    const int*   deg  = (const int*)d_in[2];
    const float* W    = (const float*)d_in[3];
    const float* bias = (const float*)d_in[4];
    float* out = (float*)d_out;

    const size_t need = (size_t)2 * NC * NO * sizeof(float)       // Wt
                      + (size_t)NB * NV * NO * sizeof(float);     // y1T
    if (ws_size >= need) {
        float* Wt = (float*)d_ws;
        float* y1 = Wt + 2 * NC * NO;
        wt_kernel<<<dim3((2 * NC * NO) / 256), 256, 0, stream>>>(W, Wt);
        dim3 grid((NV + 255) / 256, NB);
        y1_kernel<<<grid, 256, 0, stream>>>(x, Wt, y1);
        out_kernel<<<grid, 256, 0, stream>>>(x, nbr, deg, Wt, bias, y1, out);
    } else {
        fallback_kernel<<<dim3(NB * NV), 64, 0, stream>>>(x, nbr, deg, W, bias, out);
    }
}